// Round 5
// baseline (956.423 us; speedup 1.0000x reference)
//
#include <hip/hip_runtime.h>
#include <hip/hip_fp16.h>

constexpr int NN = 100000;   // nodes
constexpr int NE = 1600000;  // edges
constexpr int NG = 256;      // graphs
constexpr int NBUCK = 391;   // node buckets of 256 (391*256 = 100096 >= NN)
constexpr int NBLK = 128;    // blocks for bucket hist/scatter
constexpr int EPB = NE / NBLK;  // 12500 edges per block
constexpr int NCH = 98;      // gather chunks (98*256*4 = 100352 >= NN)

// ================= CSR build: two-level bucket counting sort =================
__global__ __launch_bounds__(256) void k_bhist(const int* __restrict__ ei,
                                               int* __restrict__ bcnt) {
  __shared__ int hc[NBUCK];
  int tid = threadIdx.x;
  for (int i = tid; i < NBUCK; i += 256) hc[i] = 0;
  __syncthreads();
  int e0 = blockIdx.x * EPB;
  for (int e = e0 + tid; e < e0 + EPB; e += 256) atomicAdd(&hc[ei[NE + e] >> 8], 1);
  __syncthreads();
  for (int i = tid; i < NBUCK; i += 256) bcnt[i * NBLK + blockIdx.x] = hc[i];
}

__global__ __launch_bounds__(1024) void k_bscan(const int* __restrict__ bcnt,
                                                int* __restrict__ boff) {
  const int NTOT = NBUCK * NBLK;  // 50048
  const int P = (NTOT + 1023) / 1024;  // 49
  __shared__ int part[1024];
  int tid = threadIdx.x;
  int lo = tid * P, hi = min(lo + P, NTOT);
  int s = 0;
  for (int i = lo; i < hi; i++) s += bcnt[i];
  part[tid] = s;
  __syncthreads();
  for (int off = 1; off < 1024; off <<= 1) {
    int v = (tid >= off) ? part[tid - off] : 0;
    __syncthreads();
    part[tid] += v;
    __syncthreads();
  }
  int run = part[tid] - s;  // exclusive
  for (int i = lo; i < hi; i++) { boff[i] = run; run += bcnt[i]; }
}

__global__ __launch_bounds__(256) void k_bscatter(const int* __restrict__ ei,
                                                  const int* __restrict__ boff,
                                                  int* __restrict__ bpacked) {
  __shared__ int cur[NBUCK];
  int tid = threadIdx.x;
  for (int i = tid; i < NBUCK; i += 256) cur[i] = boff[i * NBLK + blockIdx.x];
  __syncthreads();
  int e0 = blockIdx.x * EPB;
  for (int e = e0 + tid; e < e0 + EPB; e += 256) {
    int s = ei[e], d = ei[NE + e];
    int pos = atomicAdd(&cur[d >> 8], 1);
    bpacked[pos] = s | ((d & 255) << 17);  // src fits 17 bits (NN < 131072)
  }
}

// Per bucket: hist -> deg/dinv, local scan -> rs, cursor fill -> edata (src).
__global__ __launch_bounds__(256) void k_sortfill(const int* __restrict__ bpacked,
                                                  const int* __restrict__ boff,
                                                  float* __restrict__ dinv,
                                                  int* __restrict__ rs,
                                                  int* __restrict__ edata) {
  __shared__ int hist[256], scn[256], cur[256];
  int tid = threadIdx.x, b = blockIdx.x;
  int bs = boff[b * NBLK];
  int be = (b + 1 < NBUCK) ? boff[(b + 1) * NBLK] : NE;
  hist[tid] = 0;
  __syncthreads();
  for (int i = bs + tid; i < be; i += 256) atomicAdd(&hist[bpacked[i] >> 17], 1);
  __syncthreads();
  int n = (b << 8) + tid;
  int hv = hist[tid];
  if (n < NN) dinv[n] = rsqrtf((float)(hv + 1));  // +1 self-loop
  scn[tid] = hv;
  __syncthreads();
  for (int off = 1; off < 256; off <<= 1) {
    int v = (tid >= off) ? scn[tid - off] : 0;
    __syncthreads();
    scn[tid] += v;
    __syncthreads();
  }
  int excl = scn[tid] - hv;
  if (n < NN) rs[n] = bs + excl;
  if (b == NBUCK - 1 && tid == 0) rs[NN] = NE;
  cur[tid] = bs + excl;
  __syncthreads();
  for (int i = bs + tid; i < be; i += 256) {
    int p = bpacked[i];
    int pos = atomicAdd(&cur[p >> 17], 1);
    edata[pos] = p & 131071;  // writes confined to [bs,be) ~17KB window
  }
}

// ========== GEMM: hq[cg][n][8] = fp16( (f(in)[N][K] @ W[K][64]) * dinv[n] ) ==
// BN: apply y = relu(in*sc+sh) on input load. CB: input is column-blocked
// aggc[cg][n][8] fp32; else row-major [n][K].
template <int K, bool BN, bool CB>
__global__ __launch_bounds__(256) void k_gemm(const float* __restrict__ in,
                                              const float* __restrict__ bnp,
                                              const float* __restrict__ W,
                                              const float* __restrict__ dinv,
                                              __half* __restrict__ hq) {
  __shared__ float Wl[K * 64];
  __shared__ float xr[4][4][K];  // [wave][subrow][K]
  for (int idx = threadIdx.x; idx < K * 64; idx += 256) Wl[idx] = W[idx];
  __syncthreads();
  const int lane = threadIdx.x & 63;
  const int wv = threadIdx.x >> 6;
  const int cg = lane >> 3, off = lane & 7;
  float sc = 0.f, sh = 0.f;
  if (BN) { sc = bnp[lane]; sh = bnp[64 + lane]; }
  for (int base = blockIdx.x * 16; base < NN; base += gridDim.x * 16) {
    int r0 = base + wv * 4;
#pragma unroll
    for (int j = 0; j < 4; j++) {
      int row = r0 + j;
      float v0 = 0.f, v1 = 0.f;
      if (row < NN) {
        if (CB) v0 = in[((size_t)cg * NN + row) * 8 + off];
        else {
          v0 = in[(size_t)row * K + lane];
          if (K == 128) v1 = in[(size_t)row * K + 64 + lane];
        }
      }
      if (BN) v0 = fmaxf(v0 * sc + sh, 0.f);
      xr[wv][j][lane] = v0;
      if (K == 128) xr[wv][j][64 + lane] = v1;
    }
    // Same-wave LDS ops complete in order: no barrier needed.
    float acc0 = 0, acc1 = 0, acc2 = 0, acc3 = 0;
    const float4* x0 = (const float4*)xr[wv][0];
    const float4* x1 = (const float4*)xr[wv][1];
    const float4* x2 = (const float4*)xr[wv][2];
    const float4* x3 = (const float4*)xr[wv][3];
#pragma unroll 4
    for (int k4 = 0; k4 < K / 4; k4++) {
      float4 a0 = x0[k4], a1 = x1[k4], a2 = x2[k4], a3 = x3[k4];
      float w0 = Wl[(4 * k4 + 0) * 64 + lane];
      float w1 = Wl[(4 * k4 + 1) * 64 + lane];
      float w2 = Wl[(4 * k4 + 2) * 64 + lane];
      float w3 = Wl[(4 * k4 + 3) * 64 + lane];
      acc0 += a0.x * w0 + a0.y * w1 + a0.z * w2 + a0.w * w3;
      acc1 += a1.x * w0 + a1.y * w1 + a1.z * w2 + a1.w * w3;
      acc2 += a2.x * w0 + a2.y * w1 + a2.z * w2 + a2.w * w3;
      acc3 += a3.x * w0 + a3.y * w1 + a3.z * w2 + a3.w * w3;
    }
#pragma unroll
    for (int j = 0; j < 4; j++) {
      int row = r0 + j;
      if (row < NN) {
        float a = (j == 0) ? acc0 : (j == 1) ? acc1 : (j == 2) ? acc2 : acc3;
        hq[((size_t)cg * NN + row) * 8 + off] = __float2half(a * dinv[row]);
      }
    }
  }
}

// ====== Gather, column-split for XCD-L2 residency of hq[cg] (1.6MB) =========
// agg[d] = dinv[d] * (sum_src h'[src] + h'[d]);  h' = h*dinv (in hq).
// Block cg = blockIdx&7 (round-robin XCD heuristic). Thread = 4 nodes serial.
__global__ __launch_bounds__(256) void k_gather2(const __half* __restrict__ hq,
                                                 const int* __restrict__ edata,
                                                 const int* __restrict__ rs,
                                                 const float* __restrict__ dinv,
                                                 float* __restrict__ aggc,
                                                 float* __restrict__ partial) {
  const int cg = blockIdx.x & 7;
  const int chunk = blockIdx.x >> 3;
  const int tid = threadIdx.x;
  const __half* hbase = hq + (size_t)cg * NN * 8;
  float ss[8], sq[8];
#pragma unroll
  for (int i = 0; i < 8; i++) { ss[i] = 0.f; sq[i] = 0.f; }
  int tg = chunk * 256 + tid;
  int n0 = tg * 4, n1 = min(n0 + 4, NN);
#pragma unroll 1
  for (int n = n0; n < n1; n++) {
    int e = rs[n], e1 = rs[n + 1];
    float acc[8];
#pragma unroll
    for (int i = 0; i < 8; i++) acc[i] = 0.f;
#pragma unroll 1
    for (; e + 2 <= e1; e += 2) {
      int s0 = edata[e], s1 = edata[e + 1];
      float4 r0 = *(const float4*)(hbase + (size_t)s0 * 8);
      float4 r1 = *(const float4*)(hbase + (size_t)s1 * 8);
      const __half2* h0 = (const __half2*)&r0;
      const __half2* h1 = (const __half2*)&r1;
#pragma unroll
      for (int i = 0; i < 4; i++) {
        float2 f0 = __half22float2(h0[i]);
        float2 f1 = __half22float2(h1[i]);
        acc[2 * i] += f0.x + f1.x;
        acc[2 * i + 1] += f0.y + f1.y;
      }
    }
    if (e < e1) {
      int s0 = edata[e];
      float4 r0 = *(const float4*)(hbase + (size_t)s0 * 8);
      const __half2* h0 = (const __half2*)&r0;
#pragma unroll
      for (int i = 0; i < 4; i++) {
        float2 f0 = __half22float2(h0[i]);
        acc[2 * i] += f0.x;
        acc[2 * i + 1] += f0.y;
      }
    }
    // self term + final scale by dinv[n]
    float4 rsv = *(const float4*)(hbase + (size_t)n * 8);
    const __half2* hs = (const __half2*)&rsv;
    float dv = dinv[n];
#pragma unroll
    for (int i = 0; i < 4; i++) {
      float2 f = __half22float2(hs[i]);
      acc[2 * i] = (acc[2 * i] + f.x) * dv;
      acc[2 * i + 1] = (acc[2 * i + 1] + f.y) * dv;
    }
    float4 o0 = {acc[0], acc[1], acc[2], acc[3]};
    float4 o1 = {acc[4], acc[5], acc[6], acc[7]};
    float4* dst = (float4*)(aggc + ((size_t)cg * NN + n) * 8);
    dst[0] = o0;
    dst[1] = o1;
#pragma unroll
    for (int i = 0; i < 8; i++) { ss[i] += acc[i]; sq[i] += acc[i] * acc[i]; }
  }
  // BN-stat partials: wave shfl-reduce, then cross-wave via tiny LDS.
  const int lane = tid & 63, wv = tid >> 6;
  __shared__ float lred[4][16];
#pragma unroll
  for (int i = 0; i < 8; i++) {
    float a = ss[i], b = sq[i];
#pragma unroll
    for (int off = 32; off > 0; off >>= 1) {
      a += __shfl_down(a, off);
      b += __shfl_down(b, off);
    }
    if (lane == 0) { lred[wv][i] = a; lred[wv][8 + i] = b; }
  }
  __syncthreads();
  if (tid < 16) {
    float v = lred[0][tid] + lred[1][tid] + lred[2][tid] + lred[3][tid];
    partial[(size_t)((tid >> 3) * 64 + cg * 8 + (tid & 7)) * NCH + chunk] = v;
  }
}

// ---------------- reduce per-chunk partials -> stats[128] ----------------
__global__ void k_redstats(const float* __restrict__ partial, float* __restrict__ stats) {
  __shared__ float red[128];
  int c = blockIdx.x, t = threadIdx.x;
  float s = 0.f;
  for (int k = t; k < NCH; k += 128) s += partial[(size_t)c * NCH + k];
  red[t] = s;
  __syncthreads();
  for (int off = 64; off > 0; off >>= 1) {
    if (t < off) red[t] += red[t + off];
    __syncthreads();
  }
  if (t == 0) stats[c] = red[0];
}

// ---------------- BN params: scale/shift per column ----------------
__global__ void k_bnparams(const float* __restrict__ stats, const float* __restrict__ gam,
                           const float* __restrict__ bet, float* __restrict__ bnp) {
  int c = threadIdx.x;
  if (c < 64) {
    const float inv_n = 1.0f / NN;
    float mean = stats[c] * inv_n;
    float var = stats[64 + c] * inv_n - mean * mean;
    float sc = gam[c] * rsqrtf(var + 1e-5f);
    bnp[c] = sc;
    bnp[64 + c] = bet[c] - mean * sc;  // conv bias cancels in BN
  }
}

// -------- layer-3 apply fused with mean-pool (batch sorted); aggc input -----
__global__ __launch_bounds__(256) void k_apply_pool(const float* __restrict__ aggc,
                                                    const float* __restrict__ bnp,
                                                    const int* __restrict__ batch,
                                                    float* __restrict__ pool,
                                                    float* __restrict__ cnt) {
  const int lane = threadIdx.x & 63;
  const int cg = lane >> 3, off = lane & 7;
  const int wave = blockIdx.x * 4 + (threadIdx.x >> 6);
  const int nwaves = gridDim.x * 4;
  const int chunk = (NN + nwaves - 1) / nwaves;
  int r0 = wave * chunk;
  int r1 = min(r0 + chunk, NN);
  if (r0 >= r1) return;
  const float sc = bnp[lane], sh = bnp[64 + lane];
  const float* base = aggc + (size_t)cg * NN * 8 + off;
  int cur = batch[r0];
  float acc = 0.f, runlen = 0.f;
#pragma unroll 1
  for (int r = r0; r < r1; r++) {
    int g = batch[r];
    if (g != cur) {
      unsafeAtomicAdd(&pool[cur * 64 + lane], acc);
      if (lane == 0) unsafeAtomicAdd(&cnt[cur], runlen);
      acc = 0.f; runlen = 0.f; cur = g;
    }
    acc += fmaxf(base[(size_t)r * 8] * sc + sh, 0.f);
    runlen += 1.f;
  }
  unsafeAtomicAdd(&pool[cur * 64 + lane], acc);
  if (lane == 0) unsafeAtomicAdd(&cnt[cur], runlen);
}

__global__ void k_finalize(const float* __restrict__ pool, const float* __restrict__ cnt,
                           float* __restrict__ out) {
  int i = blockIdx.x * 256 + threadIdx.x;
  if (i < NG * 64) out[i] = pool[i] / fmaxf(cnt[i >> 6], 1.0f);
}

extern "C" void kernel_launch(void* const* d_in, const int* in_sizes, int n_in,
                              void* d_out, int out_size, void* d_ws, size_t ws_size,
                              hipStream_t stream) {
  const float* x = (const float*)d_in[0];
  const int* ei = (const int*)d_in[1];
  const int* batch = (const int*)d_in[3];
  const float* W1 = (const float*)d_in[4];
  const float* g1 = (const float*)d_in[6];
  const float* be1 = (const float*)d_in[7];
  const float* W2 = (const float*)d_in[8];
  const float* g2 = (const float*)d_in[10];
  const float* be2 = (const float*)d_in[11];
  const float* W3 = (const float*)d_in[12];
  const float* g3 = (const float*)d_in[14];
  const float* be3 = (const float*)d_in[15];
  float* out = (float*)d_out;

  char* ws = (char*)d_ws;
  float* aggc = (float*)ws;     ws += (size_t)NN * 64 * 4;        // agg, col-blocked
  __half* hq = (__half*)ws;     ws += (size_t)NN * 64 * 2;        // h*dinv, col-blocked
  int* bpacked = (int*)ws;      ws += (size_t)NE * 4;
  int* edata = (int*)ws;        ws += (size_t)NE * 4;             // src only
  int* rs = (int*)ws;           ws += 400016;                     // (NN+1)*4 padded
  float* dinv = (float*)ws;     ws += (size_t)NN * 4;
  int* bcnt = (int*)ws;         ws += (size_t)NBUCK * NBLK * 4;
  int* boff = (int*)ws;         ws += (size_t)NBUCK * NBLK * 4;
  float* partial = (float*)ws;  ws += (size_t)128 * NCH * 4;
  float* stats = (float*)ws;    ws += 512;
  float* bnp = (float*)ws;      ws += 512;
  float* pool = (float*)ws;     ws += (size_t)NG * 64 * 4;
  float* cnt = (float*)ws;      ws += (size_t)NG * 4;

  // ---- CSR build: bucket sort (no global atomics, locality-bounded writes) --
  k_bhist<<<NBLK, 256, 0, stream>>>(ei, bcnt);
  k_bscan<<<1, 1024, 0, stream>>>(bcnt, boff);
  k_bscatter<<<NBLK, 256, 0, stream>>>(ei, boff, bpacked);
  k_sortfill<<<NBUCK, 256, 0, stream>>>(bpacked, boff, dinv, rs, edata);

  const float* gs[3] = {g1, g2, g3};
  const float* bes[3] = {be1, be2, be3};
  const float* Wsr[3] = {W1, W2, W3};

  for (int layer = 0; layer < 3; layer++) {
    if (layer == 0)
      k_gemm<128, false, false><<<1024, 256, 0, stream>>>(x, nullptr, Wsr[0], dinv, hq);
    else
      k_gemm<64, true, true><<<1024, 256, 0, stream>>>(aggc, bnp, Wsr[layer], dinv, hq);
    k_gather2<<<NCH * 8, 256, 0, stream>>>(hq, edata, rs, dinv, aggc, partial);
    k_redstats<<<128, 128, 0, stream>>>(partial, stats);
    k_bnparams<<<1, 64, 0, stream>>>(stats, gs[layer], bes[layer], bnp);
    if (layer == 2) {
      hipMemsetAsync(pool, 0, (size_t)(NG * 64 + NG) * 4, stream);
      k_apply_pool<<<1024, 256, 0, stream>>>(aggc, bnp, batch, pool, cnt);
      k_finalize<<<(NG * 64 + 255) / 256, 256, 0, stream>>>(pool, cnt, out);
    }
  }
}

// Round 6
// 673.047 us; speedup vs baseline: 1.4210x; 1.4210x over previous
//
#include <hip/hip_runtime.h>
#include <hip/hip_fp16.h>

constexpr int NN = 100000;   // nodes
constexpr int NE = 1600000;  // edges
constexpr int NG = 256;      // graphs
constexpr int NBUCK = 391;   // node buckets of 256 (391*256 = 100096 >= NN)
constexpr int NBLK = 128;    // blocks for bucket hist/scatter
constexpr int EPB = NE / NBLK;  // 12500 edges per block
constexpr int GGRID = 4096;  // gather grid (blocks)

// ================= CSR build: two-level bucket counting sort =================
__global__ __launch_bounds__(256) void k_bhist(const int* __restrict__ ei,
                                               int* __restrict__ bcnt) {
  __shared__ int hc[NBUCK];
  int tid = threadIdx.x;
  for (int i = tid; i < NBUCK; i += 256) hc[i] = 0;
  __syncthreads();
  int e0 = blockIdx.x * EPB;
  for (int e = e0 + tid; e < e0 + EPB; e += 256) atomicAdd(&hc[ei[NE + e] >> 8], 1);
  __syncthreads();
  for (int i = tid; i < NBUCK; i += 256) bcnt[i * NBLK + blockIdx.x] = hc[i];
}

__global__ __launch_bounds__(1024) void k_bscan(const int* __restrict__ bcnt,
                                                int* __restrict__ boff) {
  const int NTOT = NBUCK * NBLK;  // 50048
  const int P = (NTOT + 1023) / 1024;  // 49
  __shared__ int part[1024];
  int tid = threadIdx.x;
  int lo = tid * P, hi = min(lo + P, NTOT);
  int s = 0;
  for (int i = lo; i < hi; i++) s += bcnt[i];
  part[tid] = s;
  __syncthreads();
  for (int off = 1; off < 1024; off <<= 1) {
    int v = (tid >= off) ? part[tid - off] : 0;
    __syncthreads();
    part[tid] += v;
    __syncthreads();
  }
  int run = part[tid] - s;  // exclusive
  for (int i = lo; i < hi; i++) { boff[i] = run; run += bcnt[i]; }
}

__global__ __launch_bounds__(256) void k_bscatter(const int* __restrict__ ei,
                                                  const int* __restrict__ boff,
                                                  int* __restrict__ bpacked) {
  __shared__ int cur[NBUCK];
  int tid = threadIdx.x;
  for (int i = tid; i < NBUCK; i += 256) cur[i] = boff[i * NBLK + blockIdx.x];
  __syncthreads();
  int e0 = blockIdx.x * EPB;
  for (int e = e0 + tid; e < e0 + EPB; e += 256) {
    int s = ei[e], d = ei[NE + e];
    int pos = atomicAdd(&cur[d >> 8], 1);
    bpacked[pos] = s | ((d & 255) << 17);  // src fits 17 bits (NN < 131072)
  }
}

// Per bucket: hist -> deg/dinv, local scan -> rs, cursor fill -> edata (src).
__global__ __launch_bounds__(256) void k_sortfill(const int* __restrict__ bpacked,
                                                  const int* __restrict__ boff,
                                                  float* __restrict__ dinv,
                                                  int* __restrict__ rs,
                                                  int* __restrict__ edata) {
  __shared__ int hist[256], scn[256], cur[256];
  int tid = threadIdx.x, b = blockIdx.x;
  int bs = boff[b * NBLK];
  int be = (b + 1 < NBUCK) ? boff[(b + 1) * NBLK] : NE;
  hist[tid] = 0;
  __syncthreads();
  for (int i = bs + tid; i < be; i += 256) atomicAdd(&hist[bpacked[i] >> 17], 1);
  __syncthreads();
  int n = (b << 8) + tid;
  int hv = hist[tid];
  if (n < NN) dinv[n] = rsqrtf((float)(hv + 1));  // +1 self-loop
  scn[tid] = hv;
  __syncthreads();
  for (int off = 1; off < 256; off <<= 1) {
    int v = (tid >= off) ? scn[tid - off] : 0;
    __syncthreads();
    scn[tid] += v;
    __syncthreads();
  }
  int excl = scn[tid] - hv;
  if (n < NN) rs[n] = bs + excl;
  if (b == NBUCK - 1 && tid == 0) rs[NN] = NE;
  cur[tid] = bs + excl;
  __syncthreads();
  for (int i = bs + tid; i < be; i += 256) {
    int p = bpacked[i];
    int pos = atomicAdd(&cur[p >> 17], 1);
    edata[pos] = p & 131071;  // writes confined to [bs,be) ~17KB window
  }
}

// ====== GEMM: hq[n][64] = fp16( (f(in)[N][K] @ W[K][64]) * dinv[n] ) ========
// BN: apply y = relu(in*sc+sh) on input load (fused BN+ReLU).
template <int K, bool BN>
__global__ __launch_bounds__(256) void k_gemm(const float* __restrict__ in,
                                              const float* __restrict__ bnp,
                                              const float* __restrict__ W,
                                              const float* __restrict__ dinv,
                                              __half* __restrict__ hq) {
  __shared__ float Wl[K * 64];
  __shared__ float xr[4][4][K];  // [wave][subrow][K]
  for (int idx = threadIdx.x; idx < K * 64; idx += 256) Wl[idx] = W[idx];
  __syncthreads();
  const int lane = threadIdx.x & 63;
  const int wv = threadIdx.x >> 6;
  float sc = 0.f, sh = 0.f;
  if (BN) { sc = bnp[lane]; sh = bnp[64 + lane]; }
  for (int base = blockIdx.x * 16; base < NN; base += gridDim.x * 16) {
    int r0 = base + wv * 4;
#pragma unroll
    for (int j = 0; j < 4; j++) {
      int row = r0 + j;
      float v0 = 0.f, v1 = 0.f;
      if (row < NN) {
        v0 = in[(size_t)row * K + lane];
        if (K == 128) v1 = in[(size_t)row * K + 64 + lane];
      }
      if (BN) v0 = fmaxf(v0 * sc + sh, 0.f);
      xr[wv][j][lane] = v0;
      if (K == 128) xr[wv][j][64 + lane] = v1;
    }
    // Same-wave LDS ops complete in order: no barrier needed.
    float acc0 = 0, acc1 = 0, acc2 = 0, acc3 = 0;
    const float4* x0 = (const float4*)xr[wv][0];
    const float4* x1 = (const float4*)xr[wv][1];
    const float4* x2 = (const float4*)xr[wv][2];
    const float4* x3 = (const float4*)xr[wv][3];
#pragma unroll 4
    for (int k4 = 0; k4 < K / 4; k4++) {
      float4 a0 = x0[k4], a1 = x1[k4], a2 = x2[k4], a3 = x3[k4];
      float w0 = Wl[(4 * k4 + 0) * 64 + lane];
      float w1 = Wl[(4 * k4 + 1) * 64 + lane];
      float w2 = Wl[(4 * k4 + 2) * 64 + lane];
      float w3 = Wl[(4 * k4 + 3) * 64 + lane];
      acc0 += a0.x * w0 + a0.y * w1 + a0.z * w2 + a0.w * w3;
      acc1 += a1.x * w0 + a1.y * w1 + a1.z * w2 + a1.w * w3;
      acc2 += a2.x * w0 + a2.y * w1 + a2.z * w2 + a2.w * w3;
      acc3 += a3.x * w0 + a3.y * w1 + a3.z * w2 + a3.w * w3;
    }
    if (r0 + 0 < NN) hq[(size_t)(r0 + 0) * 64 + lane] = __float2half(acc0 * dinv[r0 + 0]);
    if (r0 + 1 < NN) hq[(size_t)(r0 + 1) * 64 + lane] = __float2half(acc1 * dinv[r0 + 1]);
    if (r0 + 2 < NN) hq[(size_t)(r0 + 2) * 64 + lane] = __float2half(acc2 * dinv[r0 + 2]);
    if (r0 + 3 < NN) hq[(size_t)(r0 + 3) * 64 + lane] = __float2half(acc3 * dinv[r0 + 3]);
  }
}

// ====== Gather: agg[d] = dinv[d] * (sum_src h'[src] + h'[d]) ================
// h' = h*dinv (fp16, row = 128 B = one full line). Wave = 4 quarter-streams of
// 16 lanes; lane owns cols 4*cl..4*cl+3 (8 B load). 2-deep unroll -> 8 edges
// in flight per wave. Cross-quarter combine: 2 shfl_xor. Fused BN stats.
__global__ __launch_bounds__(256) void k_gather(const __half* __restrict__ hq,
                                                const int* __restrict__ edata,
                                                const int* __restrict__ rs,
                                                const float* __restrict__ dinv,
                                                float* __restrict__ agg,
                                                float* __restrict__ partial) {
  const int tid = threadIdx.x;
  const int lane = tid & 63;
  const int q = lane >> 4;   // quarter stream 0..3
  const int cl = lane & 15;  // column group (4 cols)
  const int wave = blockIdx.x * 4 + (tid >> 6);
  const int nwaves = GGRID * 4;
  float ss[4] = {0.f, 0.f, 0.f, 0.f}, sq4[4] = {0.f, 0.f, 0.f, 0.f};
#pragma unroll 1
  for (int node = wave; node < NN; node += nwaves) {
    int e0 = rs[node], e1 = rs[node + 1];
    float a0 = 0.f, a1 = 0.f, a2 = 0.f, a3 = 0.f;
    int e = e0 + q;
#pragma unroll 1
    for (; e + 4 < e1; e += 8) {  // 2 edges per quarter in flight
      int s0 = edata[e], s1 = edata[e + 4];
      float2 r0 = ((const float2*)(hq + (size_t)s0 * 64))[cl];
      float2 r1 = ((const float2*)(hq + (size_t)s1 * 64))[cl];
      const __half2* h0 = (const __half2*)&r0;
      const __half2* h1 = (const __half2*)&r1;
      float2 f0 = __half22float2(h0[0]), f1 = __half22float2(h0[1]);
      float2 g0 = __half22float2(h1[0]), g1 = __half22float2(h1[1]);
      a0 += f0.x + g0.x; a1 += f0.y + g0.y;
      a2 += f1.x + g1.x; a3 += f1.y + g1.y;
    }
    if (e < e1) {
      int s0 = edata[e];
      float2 r0 = ((const float2*)(hq + (size_t)s0 * 64))[cl];
      const __half2* h0 = (const __half2*)&r0;
      float2 f0 = __half22float2(h0[0]), f1 = __half22float2(h0[1]);
      a0 += f0.x; a1 += f0.y; a2 += f1.x; a3 += f1.y;
    }
    // combine 4 quarter-streams (all lanes end with full sums)
    a0 += __shfl_xor(a0, 16); a1 += __shfl_xor(a1, 16);
    a2 += __shfl_xor(a2, 16); a3 += __shfl_xor(a3, 16);
    a0 += __shfl_xor(a0, 32); a1 += __shfl_xor(a1, 32);
    a2 += __shfl_xor(a2, 32); a3 += __shfl_xor(a3, 32);
    if (q == 0) {
      // self term + final scale by dinv[node]
      float2 rsv = ((const float2*)(hq + (size_t)node * 64))[cl];
      const __half2* hs = (const __half2*)&rsv;
      float2 f0 = __half22float2(hs[0]), f1 = __half22float2(hs[1]);
      float dv = dinv[node];
      a0 = (a0 + f0.x) * dv; a1 = (a1 + f0.y) * dv;
      a2 = (a2 + f1.x) * dv; a3 = (a3 + f1.y) * dv;
      float4 o = {a0, a1, a2, a3};
      ((float4*)(agg + (size_t)node * 64))[cl] = o;
      ss[0] += a0; ss[1] += a1; ss[2] += a2; ss[3] += a3;
      sq4[0] += a0 * a0; sq4[1] += a1 * a1; sq4[2] += a2 * a2; sq4[3] += a3 * a3;
    }
  }
  // BN-stat partials: q0 lanes hold col sums; reduce across the 4 waves in LDS.
  __shared__ float red[2][4][64];
  const int wv = tid >> 6;
  if (q == 0) {
#pragma unroll
    for (int i = 0; i < 4; i++) {
      red[0][wv][4 * cl + i] = ss[i];
      red[1][wv][4 * cl + i] = sq4[i];
    }
  }
  __syncthreads();
  if (tid < 128) {
    int s = tid >> 6, c = tid & 63;
    float v = red[s][0][c] + red[s][1][c] + red[s][2][c] + red[s][3][c];
    partial[(size_t)(s * 64 + c) * GGRID + blockIdx.x] = v;
  }
}

// ---------------- reduce per-block partials -> stats[128] ----------------
__global__ void k_redstats(const float* __restrict__ partial, float* __restrict__ stats) {
  __shared__ float red[128];
  int c = blockIdx.x, t = threadIdx.x;
  float s = 0.f;
  for (int k = t; k < GGRID; k += 128) s += partial[(size_t)c * GGRID + k];
  red[t] = s;
  __syncthreads();
  for (int off = 64; off > 0; off >>= 1) {
    if (t < off) red[t] += red[t + off];
    __syncthreads();
  }
  if (t == 0) stats[c] = red[0];
}

// ---------------- BN params: scale/shift per column ----------------
__global__ void k_bnparams(const float* __restrict__ stats, const float* __restrict__ gam,
                           const float* __restrict__ bet, float* __restrict__ bnp) {
  int c = threadIdx.x;
  if (c < 64) {
    const float inv_n = 1.0f / NN;
    float mean = stats[c] * inv_n;
    float var = stats[64 + c] * inv_n - mean * mean;
    float sc = gam[c] * rsqrtf(var + 1e-5f);
    bnp[c] = sc;
    bnp[64 + c] = bet[c] - mean * sc;  // conv bias cancels in BN
  }
}

// ---------------- layer-3 apply fused with mean-pool (batch sorted) ---------
__global__ __launch_bounds__(256) void k_apply_pool(const float* __restrict__ agg,
                                                    const float* __restrict__ bnp,
                                                    const int* __restrict__ batch,
                                                    float* __restrict__ pool,
                                                    float* __restrict__ cnt) {
  const int lane = threadIdx.x & 63;
  const int wave = blockIdx.x * 4 + (threadIdx.x >> 6);
  const int nwaves = gridDim.x * 4;
  const int chunk = (NN + nwaves - 1) / nwaves;
  int r0 = wave * chunk;
  int r1 = min(r0 + chunk, NN);
  if (r0 >= r1) return;
  const float sc = bnp[lane], sh = bnp[64 + lane];
  int cur = batch[r0];
  float acc = 0.f, runlen = 0.f;
#pragma unroll 1
  for (int r = r0; r < r1; r++) {
    int g = batch[r];
    if (g != cur) {
      unsafeAtomicAdd(&pool[cur * 64 + lane], acc);
      if (lane == 0) unsafeAtomicAdd(&cnt[cur], runlen);
      acc = 0.f; runlen = 0.f; cur = g;
    }
    acc += fmaxf(agg[(size_t)r * 64 + lane] * sc + sh, 0.f);
    runlen += 1.f;
  }
  unsafeAtomicAdd(&pool[cur * 64 + lane], acc);
  if (lane == 0) unsafeAtomicAdd(&cnt[cur], runlen);
}

__global__ void k_finalize(const float* __restrict__ pool, const float* __restrict__ cnt,
                           float* __restrict__ out) {
  int i = blockIdx.x * 256 + threadIdx.x;
  if (i < NG * 64) out[i] = pool[i] / fmaxf(cnt[i >> 6], 1.0f);
}

extern "C" void kernel_launch(void* const* d_in, const int* in_sizes, int n_in,
                              void* d_out, int out_size, void* d_ws, size_t ws_size,
                              hipStream_t stream) {
  const float* x = (const float*)d_in[0];
  const int* ei = (const int*)d_in[1];
  const int* batch = (const int*)d_in[3];
  const float* W1 = (const float*)d_in[4];
  const float* g1 = (const float*)d_in[6];
  const float* be1 = (const float*)d_in[7];
  const float* W2 = (const float*)d_in[8];
  const float* g2 = (const float*)d_in[10];
  const float* be2 = (const float*)d_in[11];
  const float* W3 = (const float*)d_in[12];
  const float* g3 = (const float*)d_in[14];
  const float* be3 = (const float*)d_in[15];
  float* out = (float*)d_out;

  char* ws = (char*)d_ws;
  float* agg = (float*)ws;      ws += (size_t)NN * 64 * 4;   // agg, row-major fp32
  __half* hq = (__half*)ws;     ws += (size_t)NN * 64 * 2;   // h*dinv, row-major fp16
  int* bpacked = (int*)ws;      ws += (size_t)NE * 4;
  int* edata = (int*)ws;        ws += (size_t)NE * 4;        // src only, dst-sorted
  int* rs = (int*)ws;           ws += 400016;                // (NN+1)*4 padded
  float* dinv = (float*)ws;     ws += (size_t)NN * 4;
  int* bcnt = (int*)ws;         ws += (size_t)NBUCK * NBLK * 4;
  int* boff = (int*)ws;         ws += (size_t)NBUCK * NBLK * 4;
  float* partial = (float*)ws;  ws += (size_t)128 * GGRID * 4;
  float* stats = (float*)ws;    ws += 512;
  float* bnp = (float*)ws;      ws += 512;
  float* pool = (float*)ws;     ws += (size_t)NG * 64 * 4;
  float* cnt = (float*)ws;      ws += (size_t)NG * 4;

  // ---- CSR build: bucket sort (no global atomics, locality-bounded writes) --
  k_bhist<<<NBLK, 256, 0, stream>>>(ei, bcnt);
  k_bscan<<<1, 1024, 0, stream>>>(bcnt, boff);
  k_bscatter<<<NBLK, 256, 0, stream>>>(ei, boff, bpacked);
  k_sortfill<<<NBUCK, 256, 0, stream>>>(bpacked, boff, dinv, rs, edata);

  const float* gs[3] = {g1, g2, g3};
  const float* bes[3] = {be1, be2, be3};
  const float* Wsr[3] = {W1, W2, W3};

  for (int layer = 0; layer < 3; layer++) {
    if (layer == 0)
      k_gemm<128, false><<<1024, 256, 0, stream>>>(x, nullptr, Wsr[0], dinv, hq);
    else
      k_gemm<64, true><<<1024, 256, 0, stream>>>(agg, bnp, Wsr[layer], dinv, hq);
    k_gather<<<GGRID, 256, 0, stream>>>(hq, edata, rs, dinv, agg, partial);
    k_redstats<<<128, 128, 0, stream>>>(partial, stats);
    k_bnparams<<<1, 64, 0, stream>>>(stats, gs[layer], bes[layer], bnp);
    if (layer == 2) {
      hipMemsetAsync(pool, 0, (size_t)(NG * 64 + NG) * 4, stream);
      k_apply_pool<<<1024, 256, 0, stream>>>(agg, bnp, batch, pool, cnt);
      k_finalize<<<(NG * 64 + 255) / 256, 256, 0, stream>>>(pool, cnt, out);
    }
  }
}

// Round 7
// 604.664 us; speedup vs baseline: 1.5817x; 1.1131x over previous
//
#include <hip/hip_runtime.h>
#include <hip/hip_fp16.h>

constexpr int NN = 100000;   // nodes
constexpr int NE = 1600000;  // edges
constexpr int NG = 256;      // graphs
constexpr int NBUCK = 391;   // node buckets of 256 (391*256 = 100096 >= NN)
constexpr int NBLK = 128;    // blocks for bucket hist/scatter
constexpr int EPB = NE / NBLK;  // 12500 edges per block
constexpr int GGRID = 4096;  // gather grid (blocks)

// ================= CSR build: two-level bucket counting sort =================
__global__ __launch_bounds__(256) void k_bhist(const int* __restrict__ ei,
                                               int* __restrict__ bcnt) {
  __shared__ int hc[NBUCK];
  int tid = threadIdx.x;
  for (int i = tid; i < NBUCK; i += 256) hc[i] = 0;
  __syncthreads();
  int e0 = blockIdx.x * EPB;
  for (int e = e0 + tid; e < e0 + EPB; e += 256) atomicAdd(&hc[ei[NE + e] >> 8], 1);
  __syncthreads();
  for (int i = tid; i < NBUCK; i += 256) bcnt[i * NBLK + blockIdx.x] = hc[i];
}

// ---- hierarchical scan of bcnt[NBUCK][NBLK] -> boff (exclusive, row-major) --
__global__ __launch_bounds__(128) void k_scan1(const int* __restrict__ bcnt,
                                               int* __restrict__ boff,
                                               int* __restrict__ btot) {
  __shared__ int s[128];
  int t = threadIdx.x, b = blockIdx.x;
  int v = bcnt[b * NBLK + t];
  s[t] = v;
  __syncthreads();
  for (int off = 1; off < 128; off <<= 1) {
    int x = (t >= off) ? s[t - off] : 0;
    __syncthreads();
    s[t] += x;
    __syncthreads();
  }
  boff[b * NBLK + t] = s[t] - v;  // local exclusive
  if (t == 127) btot[b] = s[127];
}

__global__ __launch_bounds__(512) void k_scan2(const int* __restrict__ btot,
                                               int* __restrict__ bbase) {
  __shared__ int s[512];
  int t = threadIdx.x;
  int v = (t < NBUCK) ? btot[t] : 0;
  s[t] = v;
  __syncthreads();
  for (int off = 1; off < 512; off <<= 1) {
    int x = (t >= off) ? s[t - off] : 0;
    __syncthreads();
    s[t] += x;
    __syncthreads();
  }
  if (t < NBUCK) bbase[t] = s[t] - v;  // exclusive
}

__global__ __launch_bounds__(128) void k_scan3(int* __restrict__ boff,
                                               const int* __restrict__ bbase) {
  int t = threadIdx.x, b = blockIdx.x;
  boff[b * NBLK + t] += bbase[b];
}

__global__ __launch_bounds__(256) void k_bscatter(const int* __restrict__ ei,
                                                  const int* __restrict__ boff,
                                                  int* __restrict__ bpacked) {
  __shared__ int cur[NBUCK];
  int tid = threadIdx.x;
  for (int i = tid; i < NBUCK; i += 256) cur[i] = boff[i * NBLK + blockIdx.x];
  __syncthreads();
  int e0 = blockIdx.x * EPB;
  for (int e = e0 + tid; e < e0 + EPB; e += 256) {
    int s = ei[e], d = ei[NE + e];
    int pos = atomicAdd(&cur[d >> 8], 1);
    bpacked[pos] = s | ((d & 255) << 17);  // src fits 17 bits (NN < 131072)
  }
}

// Per bucket: hist -> deg/dinv, local scan -> rs, cursor fill -> edata (src).
__global__ __launch_bounds__(256) void k_sortfill(const int* __restrict__ bpacked,
                                                  const int* __restrict__ boff,
                                                  float* __restrict__ dinv,
                                                  int* __restrict__ rs,
                                                  int* __restrict__ edata) {
  __shared__ int hist[256], scn[256], cur[256];
  int tid = threadIdx.x, b = blockIdx.x;
  int bs = boff[b * NBLK];
  int be = (b + 1 < NBUCK) ? boff[(b + 1) * NBLK] : NE;
  hist[tid] = 0;
  __syncthreads();
  for (int i = bs + tid; i < be; i += 256) atomicAdd(&hist[bpacked[i] >> 17], 1);
  __syncthreads();
  int n = (b << 8) + tid;
  int hv = hist[tid];
  if (n < NN) dinv[n] = rsqrtf((float)(hv + 1));  // +1 self-loop
  scn[tid] = hv;
  __syncthreads();
  for (int off = 1; off < 256; off <<= 1) {
    int v = (tid >= off) ? scn[tid - off] : 0;
    __syncthreads();
    scn[tid] += v;
    __syncthreads();
  }
  int excl = scn[tid] - hv;
  if (n < NN) rs[n] = bs + excl;
  if (b == NBUCK - 1 && tid == 0) rs[NN] = NE;
  cur[tid] = bs + excl;
  __syncthreads();
  for (int i = bs + tid; i < be; i += 256) {
    int p = bpacked[i];
    int pos = atomicAdd(&cur[p >> 17], 1);
    edata[pos] = p & 131071;  // writes confined to [bs,be) ~17KB window
  }
}

// ====== GEMM: hq[n][64] = fp16( (f(in)[N][K] @ W[K][64]) * dinv[n] ) ========
// BN: apply y = relu(in*sc+sh) on input load (fused BN+ReLU).
template <int K, bool BN>
__global__ __launch_bounds__(256) void k_gemm(const float* __restrict__ in,
                                              const float* __restrict__ bnp,
                                              const float* __restrict__ W,
                                              const float* __restrict__ dinv,
                                              __half* __restrict__ hq) {
  __shared__ float Wl[K * 64];
  __shared__ float xr[4][4][K];  // [wave][subrow][K]
  for (int idx = threadIdx.x; idx < K * 64; idx += 256) Wl[idx] = W[idx];
  __syncthreads();
  const int lane = threadIdx.x & 63;
  const int wv = threadIdx.x >> 6;
  float sc = 0.f, sh = 0.f;
  if (BN) { sc = bnp[lane]; sh = bnp[64 + lane]; }
  for (int base = blockIdx.x * 16; base < NN; base += gridDim.x * 16) {
    int r0 = base + wv * 4;
#pragma unroll
    for (int j = 0; j < 4; j++) {
      int row = r0 + j;
      float v0 = 0.f, v1 = 0.f;
      if (row < NN) {
        v0 = in[(size_t)row * K + lane];
        if (K == 128) v1 = in[(size_t)row * K + 64 + lane];
      }
      if (BN) v0 = fmaxf(v0 * sc + sh, 0.f);
      xr[wv][j][lane] = v0;
      if (K == 128) xr[wv][j][64 + lane] = v1;
    }
    // Same-wave LDS ops complete in order: no barrier needed.
    float acc0 = 0, acc1 = 0, acc2 = 0, acc3 = 0;
    const float4* x0 = (const float4*)xr[wv][0];
    const float4* x1 = (const float4*)xr[wv][1];
    const float4* x2 = (const float4*)xr[wv][2];
    const float4* x3 = (const float4*)xr[wv][3];
#pragma unroll 4
    for (int k4 = 0; k4 < K / 4; k4++) {
      float4 a0 = x0[k4], a1 = x1[k4], a2 = x2[k4], a3 = x3[k4];
      float w0 = Wl[(4 * k4 + 0) * 64 + lane];
      float w1 = Wl[(4 * k4 + 1) * 64 + lane];
      float w2 = Wl[(4 * k4 + 2) * 64 + lane];
      float w3 = Wl[(4 * k4 + 3) * 64 + lane];
      acc0 += a0.x * w0 + a0.y * w1 + a0.z * w2 + a0.w * w3;
      acc1 += a1.x * w0 + a1.y * w1 + a1.z * w2 + a1.w * w3;
      acc2 += a2.x * w0 + a2.y * w1 + a2.z * w2 + a2.w * w3;
      acc3 += a3.x * w0 + a3.y * w1 + a3.z * w2 + a3.w * w3;
    }
    if (r0 + 0 < NN) hq[(size_t)(r0 + 0) * 64 + lane] = __float2half(acc0 * dinv[r0 + 0]);
    if (r0 + 1 < NN) hq[(size_t)(r0 + 1) * 64 + lane] = __float2half(acc1 * dinv[r0 + 1]);
    if (r0 + 2 < NN) hq[(size_t)(r0 + 2) * 64 + lane] = __float2half(acc2 * dinv[r0 + 2]);
    if (r0 + 3 < NN) hq[(size_t)(r0 + 3) * 64 + lane] = __float2half(acc3 * dinv[r0 + 3]);
  }
}

// ====== Gather: agg[d] = dinv[d] * (sum_src h'[src] + h'[d]) ================
// h' = h*dinv (fp16, row = 128 B = one full line). Wave = 4 quarter-streams of
// 16 lanes; lane owns cols 4*cl..4*cl+3 (8 B load). 2-deep unroll -> 8 edges
// in flight per wave. Cross-quarter combine: 2 shfl_xor. Fused BN stats.
__global__ __launch_bounds__(256) void k_gather(const __half* __restrict__ hq,
                                                const int* __restrict__ edata,
                                                const int* __restrict__ rs,
                                                const float* __restrict__ dinv,
                                                float* __restrict__ agg,
                                                float* __restrict__ partial) {
  const int tid = threadIdx.x;
  const int lane = tid & 63;
  const int q = lane >> 4;   // quarter stream 0..3
  const int cl = lane & 15;  // column group (4 cols)
  const int wave = blockIdx.x * 4 + (tid >> 6);
  const int nwaves = GGRID * 4;
  float ss[4] = {0.f, 0.f, 0.f, 0.f}, sq4[4] = {0.f, 0.f, 0.f, 0.f};
#pragma unroll 1
  for (int node = wave; node < NN; node += nwaves) {
    int e0 = rs[node], e1 = rs[node + 1];
    float a0 = 0.f, a1 = 0.f, a2 = 0.f, a3 = 0.f;
    int e = e0 + q;
#pragma unroll 1
    for (; e + 4 < e1; e += 8) {  // 2 edges per quarter in flight
      int s0 = edata[e], s1 = edata[e + 4];
      float2 r0 = ((const float2*)(hq + (size_t)s0 * 64))[cl];
      float2 r1 = ((const float2*)(hq + (size_t)s1 * 64))[cl];
      const __half2* h0 = (const __half2*)&r0;
      const __half2* h1 = (const __half2*)&r1;
      float2 f0 = __half22float2(h0[0]), f1 = __half22float2(h0[1]);
      float2 g0 = __half22float2(h1[0]), g1 = __half22float2(h1[1]);
      a0 += f0.x + g0.x; a1 += f0.y + g0.y;
      a2 += f1.x + g1.x; a3 += f1.y + g1.y;
    }
    if (e < e1) {
      int s0 = edata[e];
      float2 r0 = ((const float2*)(hq + (size_t)s0 * 64))[cl];
      const __half2* h0 = (const __half2*)&r0;
      float2 f0 = __half22float2(h0[0]), f1 = __half22float2(h0[1]);
      a0 += f0.x; a1 += f0.y; a2 += f1.x; a3 += f1.y;
    }
    // combine 4 quarter-streams (all lanes end with full sums)
    a0 += __shfl_xor(a0, 16); a1 += __shfl_xor(a1, 16);
    a2 += __shfl_xor(a2, 16); a3 += __shfl_xor(a3, 16);
    a0 += __shfl_xor(a0, 32); a1 += __shfl_xor(a1, 32);
    a2 += __shfl_xor(a2, 32); a3 += __shfl_xor(a3, 32);
    if (q == 0) {
      // self term + final scale by dinv[node]
      float2 rsv = ((const float2*)(hq + (size_t)node * 64))[cl];
      const __half2* hs = (const __half2*)&rsv;
      float2 f0 = __half22float2(hs[0]), f1 = __half22float2(hs[1]);
      float dv = dinv[node];
      a0 = (a0 + f0.x) * dv; a1 = (a1 + f0.y) * dv;
      a2 = (a2 + f1.x) * dv; a3 = (a3 + f1.y) * dv;
      float4 o = {a0, a1, a2, a3};
      ((float4*)(agg + (size_t)node * 64))[cl] = o;
      ss[0] += a0; ss[1] += a1; ss[2] += a2; ss[3] += a3;
      sq4[0] += a0 * a0; sq4[1] += a1 * a1; sq4[2] += a2 * a2; sq4[3] += a3 * a3;
    }
  }
  // BN-stat partials: q0 lanes hold col sums; reduce across the 4 waves in LDS.
  __shared__ float red[2][4][64];
  const int wv = tid >> 6;
  if (q == 0) {
#pragma unroll
    for (int i = 0; i < 4; i++) {
      red[0][wv][4 * cl + i] = ss[i];
      red[1][wv][4 * cl + i] = sq4[i];
    }
  }
  __syncthreads();
  if (tid < 128) {
    int s = tid >> 6, c = tid & 63;
    float v = red[s][0][c] + red[s][1][c] + red[s][2][c] + red[s][3][c];
    partial[(size_t)(s * 64 + c) * GGRID + blockIdx.x] = v;
  }
}

// ---------------- reduce per-block partials -> stats[128] ----------------
__global__ void k_redstats(const float* __restrict__ partial, float* __restrict__ stats) {
  __shared__ float red[128];
  int c = blockIdx.x, t = threadIdx.x;
  float s = 0.f;
  for (int k = t; k < GGRID; k += 128) s += partial[(size_t)c * GGRID + k];
  red[t] = s;
  __syncthreads();
  for (int off = 64; off > 0; off >>= 1) {
    if (t < off) red[t] += red[t + off];
    __syncthreads();
  }
  if (t == 0) stats[c] = red[0];
}

// ---------------- BN params: scale/shift per column ----------------
__global__ void k_bnparams(const float* __restrict__ stats, const float* __restrict__ gam,
                           const float* __restrict__ bet, float* __restrict__ bnp) {
  int c = threadIdx.x;
  if (c < 64) {
    const float inv_n = 1.0f / NN;
    float mean = stats[c] * inv_n;
    float var = stats[64 + c] * inv_n - mean * mean;
    float sc = gam[c] * rsqrtf(var + 1e-5f);
    bnp[c] = sc;
    bnp[64 + c] = bet[c] - mean * sc;  // conv bias cancels in BN
  }
}

// ---------------- layer-3 apply fused with mean-pool (batch sorted) ---------
__global__ __launch_bounds__(256) void k_apply_pool(const float* __restrict__ agg,
                                                    const float* __restrict__ bnp,
                                                    const int* __restrict__ batch,
                                                    float* __restrict__ pool,
                                                    float* __restrict__ cnt) {
  const int lane = threadIdx.x & 63;
  const int wave = blockIdx.x * 4 + (threadIdx.x >> 6);
  const int nwaves = gridDim.x * 4;
  const int chunk = (NN + nwaves - 1) / nwaves;
  int r0 = wave * chunk;
  int r1 = min(r0 + chunk, NN);
  if (r0 >= r1) return;
  const float sc = bnp[lane], sh = bnp[64 + lane];
  int cur = batch[r0];
  float acc = 0.f, runlen = 0.f;
#pragma unroll 1
  for (int r = r0; r < r1; r++) {
    int g = batch[r];
    if (g != cur) {
      unsafeAtomicAdd(&pool[cur * 64 + lane], acc);
      if (lane == 0) unsafeAtomicAdd(&cnt[cur], runlen);
      acc = 0.f; runlen = 0.f; cur = g;
    }
    acc += fmaxf(agg[(size_t)r * 64 + lane] * sc + sh, 0.f);
    runlen += 1.f;
  }
  unsafeAtomicAdd(&pool[cur * 64 + lane], acc);
  if (lane == 0) unsafeAtomicAdd(&cnt[cur], runlen);
}

__global__ void k_finalize(const float* __restrict__ pool, const float* __restrict__ cnt,
                           float* __restrict__ out) {
  int i = blockIdx.x * 256 + threadIdx.x;
  if (i < NG * 64) out[i] = pool[i] / fmaxf(cnt[i >> 6], 1.0f);
}

extern "C" void kernel_launch(void* const* d_in, const int* in_sizes, int n_in,
                              void* d_out, int out_size, void* d_ws, size_t ws_size,
                              hipStream_t stream) {
  const float* x = (const float*)d_in[0];
  const int* ei = (const int*)d_in[1];
  const int* batch = (const int*)d_in[3];
  const float* W1 = (const float*)d_in[4];
  const float* g1 = (const float*)d_in[6];
  const float* be1 = (const float*)d_in[7];
  const float* W2 = (const float*)d_in[8];
  const float* g2 = (const float*)d_in[10];
  const float* be2 = (const float*)d_in[11];
  const float* W3 = (const float*)d_in[12];
  const float* g3 = (const float*)d_in[14];
  const float* be3 = (const float*)d_in[15];
  float* out = (float*)d_out;

  char* ws = (char*)d_ws;
  float* agg = (float*)ws;      ws += (size_t)NN * 64 * 4;   // agg, row-major fp32
  __half* hq = (__half*)ws;     ws += (size_t)NN * 64 * 2;   // h*dinv, row-major fp16
  int* bpacked = (int*)ws;      ws += (size_t)NE * 4;
  int* edata = (int*)ws;        ws += (size_t)NE * 4;        // src only, dst-sorted
  int* rs = (int*)ws;           ws += 400016;                // (NN+1)*4 padded
  float* dinv = (float*)ws;     ws += (size_t)NN * 4;
  int* bcnt = (int*)ws;         ws += (size_t)NBUCK * NBLK * 4;
  int* boff = (int*)ws;         ws += (size_t)NBUCK * NBLK * 4;
  int* btot = (int*)ws;         ws += 512 * 4;
  int* bbase = (int*)ws;        ws += 512 * 4;
  float* partial = (float*)ws;  ws += (size_t)128 * GGRID * 4;
  float* stats = (float*)ws;    ws += 512;
  float* bnp = (float*)ws;      ws += 512;
  float* pool = (float*)ws;     ws += (size_t)NG * 64 * 4;
  float* cnt = (float*)ws;      ws += (size_t)NG * 4;

  // ---- CSR build: bucket sort (no global atomics, locality-bounded writes) --
  k_bhist<<<NBLK, 256, 0, stream>>>(ei, bcnt);
  k_scan1<<<NBUCK, 128, 0, stream>>>(bcnt, boff, btot);
  k_scan2<<<1, 512, 0, stream>>>(btot, bbase);
  k_scan3<<<NBUCK, 128, 0, stream>>>(boff, bbase);
  k_bscatter<<<NBLK, 256, 0, stream>>>(ei, boff, bpacked);
  k_sortfill<<<NBUCK, 256, 0, stream>>>(bpacked, boff, dinv, rs, edata);

  const float* gs[3] = {g1, g2, g3};
  const float* bes[3] = {be1, be2, be3};
  const float* Wsr[3] = {W1, W2, W3};

  for (int layer = 0; layer < 3; layer++) {
    if (layer == 0)
      k_gemm<128, false><<<1024, 256, 0, stream>>>(x, nullptr, Wsr[0], dinv, hq);
    else
      k_gemm<64, true><<<1024, 256, 0, stream>>>(agg, bnp, Wsr[layer], dinv, hq);
    k_gather<<<GGRID, 256, 0, stream>>>(hq, edata, rs, dinv, agg, partial);
    k_redstats<<<128, 128, 0, stream>>>(partial, stats);
    k_bnparams<<<1, 64, 0, stream>>>(stats, gs[layer], bes[layer], bnp);
    if (layer == 2) {
      hipMemsetAsync(pool, 0, (size_t)(NG * 64 + NG) * 4, stream);
      k_apply_pool<<<1024, 256, 0, stream>>>(agg, bnp, batch, pool, cnt);
      k_finalize<<<(NG * 64 + 255) / 256, 256, 0, stream>>>(pool, cnt, out);
    }
  }
}